// Round 8
// baseline (2588.999 us; speedup 1.0000x reference)
//
#include <hip/hip_runtime.h>
#include <cstdint>
#include <cstddef>

#define NLV 12
#define NPL 10000
#define KE 3
#define EPL (NPL * KE)   // 30000
#define NE (11 * EPL)    // 330000
#define NT (NLV * NPL)   // 120000
#define H 100
#define H2 50
#define FD 4
#define DM 30
#define AP 52            // pre50 / smA / smP row stride (13 float4)
#define TN 40            // nodes per block (250 blocks exactly)
#define YS 404           // Y LDS row stride (dwords)
#define HSS 104          // hs LDS row stride
#define NWS 108          // nwT row stride

__device__ __forceinline__ float sigmoidf_(float x) {
    return 1.0f / (1.0f + __expf(-x));
}
__device__ __forceinline__ float tanhf_(float x) {
    float e = __expf(2.0f * x);
    return 1.0f - 2.0f / (e + 1.0f);
}

// ---------------------------------------------------------------------------
// Weight folding per direction (PER = 28350 outputs)  [round-5 verbatim]:
//  WaT[c*52+k] = (w2@pw1)[k][c] ;  b2p[c] = (b2@pw1)[c]
//  W4i[k*400+c]  c=4o+g, k<50:  g0: pw2[k][o]; g1..3: sum_m pw2[k][m]*wh[(g-1)*100+o][m]
//  b4i[c]: g0: pb2[o]; g1: bh[o]+fold+bi[o]; g2: bh[100+o]+fold+bi[100+o]; g3: bh[200+o]+fold
//  nwT[c*108+k] = (k<100) ? w1pre[k*50+c] : 0
// ---------------------------------------------------------------------------
__global__ void fold_kernel(
    const float* __restrict__ w2F, const float* __restrict__ b2F_,
    const float* __restrict__ pw1F, const float* __restrict__ pw2F,
    const float* __restrict__ pb2F, const float* __restrict__ whF,
    const float* __restrict__ bhF, const float* __restrict__ biF,
    const float* __restrict__ w1pF,
    const float* __restrict__ w2B, const float* __restrict__ b2B_,
    const float* __restrict__ pw1B, const float* __restrict__ pw2B,
    const float* __restrict__ pb2B, const float* __restrict__ whB,
    const float* __restrict__ bhB, const float* __restrict__ biB,
    const float* __restrict__ w1pB,
    float* __restrict__ WaTF, float* __restrict__ b2pF,
    float* __restrict__ W4iF, float* __restrict__ b4iF, float* __restrict__ nwTF,
    float* __restrict__ WaTB, float* __restrict__ b2pB,
    float* __restrict__ W4iB, float* __restrict__ b4iB, float* __restrict__ nwTB)
{
    const int PER = 28350;
    int gid = blockIdx.x * blockDim.x + threadIdx.x;
    if (gid >= 2 * PER) return;
    int dir = gid / PER;
    int i = gid - dir * PER;
    const float* w2  = dir ? w2B  : w2F;
    const float* b2  = dir ? b2B_ : b2F_;
    const float* pw1 = dir ? pw1B : pw1F;
    const float* pw2 = dir ? pw2B : pw2F;
    const float* wh  = dir ? whB  : whF;
    const float* bh  = dir ? bhB  : bhF;
    const float* bi  = dir ? biB  : biF;
    const float* pb2 = dir ? pb2B : pb2F;
    const float* w1p = dir ? w1pB : w1pF;
    float* WaT = dir ? WaTB : WaTF;
    float* b2p = dir ? b2pB : b2pF;
    float* W4i = dir ? W4iB : W4iF;
    float* b4i = dir ? b4iB : b4iF;
    float* nwT = dir ? nwTB : nwTF;

    if (i < 2500) {
        int c = i / 50, k = i - c * 50;
        float s = 0.f;
        for (int m = 0; m < 100; ++m) s += w2[k * 100 + m] * pw1[m * 50 + c];
        WaT[c * AP + k] = s;
    } else if (i < 2550) {
        int c = i - 2500;
        float s = 0.f;
        for (int m = 0; m < 100; ++m) s += b2[m] * pw1[m * 50 + c];
        b2p[c] = s;
    } else if (i < 22550) {
        int j = i - 2550;
        int k = j / 400, c = j - k * 400;
        int o = c >> 2, g = c & 3;
        float s;
        if (g == 0) {
            s = pw2[k * 100 + o];
        } else {
            int row = (g - 1) * 100 + o;
            s = 0.f;
            for (int m = 0; m < 100; ++m) s += pw2[k * 100 + m] * wh[row * 100 + m];
        }
        W4i[k * 400 + c] = s;
    } else if (i < 22950) {
        int c = i - 22550;
        int o = c >> 2, g = c & 3;
        float s;
        if (g == 0) {
            s = pb2[o];
        } else {
            int row = (g - 1) * 100 + o;
            s = bh[row];
            for (int m = 0; m < 100; ++m) s += pb2[m] * wh[row * 100 + m];
            if (g == 1) s += bi[o];
            else if (g == 2) s += bi[100 + o];
        }
        b4i[c] = s;
    } else {
        int j = i - 22950;
        int c = j / NWS, k = j - c * NWS;
        nwT[c * NWS + k] = (k < 100) ? w1p[k * 50 + c] : 0.f;
    }
}

// ---------------------------------------------------------------------------
// CSR build (grouped by src; LOCAL dst indices). counts = in-degree.
// ---------------------------------------------------------------------------
__global__ void csr_count(const int* __restrict__ src, int* __restrict__ counts)
{
    int e = blockIdx.x * blockDim.x + threadIdx.x;
    if (e >= NE) return;
    int f = e / EPL;
    atomicAdd(&counts[f * NPL + src[e] - f * NPL], 1);
}

__global__ void csr_scan(const int* __restrict__ counts, int* __restrict__ offs)
{
    int f = blockIdx.x;
    int t = threadIdx.x;
    const int base = f * NPL;
    const int CH = 40;
    __shared__ int part[256];
    int s = 0;
    for (int k = 0; k < CH; ++k) {
        int idx = t * CH + k;
        if (idx < NPL) s += counts[base + idx];
    }
    part[t] = s;
    __syncthreads();
    if (t == 0) {
        int run = 0;
        for (int j = 0; j < 256; ++j) { int tmp = part[j]; part[j] = run; run += tmp; }
    }
    __syncthreads();
    int run = part[t];
    for (int k = 0; k < CH; ++k) {
        int idx = t * CH + k;
        if (idx < NPL) { offs[base + idx] = run; run += counts[base + idx]; }
    }
}

__global__ void csr_fill(const int* __restrict__ src, const int* __restrict__ dst,
                         const int* __restrict__ offs, int* __restrict__ cursor,
                         int* __restrict__ nbrb)
{
    int e = blockIdx.x * blockDim.x + threadIdx.x;
    if (e >= NE) return;
    int f = e / EPL;
    int sl = src[e] - f * NPL;
    int p = atomicAdd(&cursor[f * NPL + sl], 1);
    nbrb[f * EPL + offs[f * NPL + sl] + p] = dst[e] - (f + 1) * NPL;
}

__global__ void pre_init(const float* __restrict__ b1,
                         float* __restrict__ pre0, float* __restrict__ pre1)
{
    int t = blockIdx.x * blockDim.x + threadIdx.x;
    if (t >= NPL * AP) return;
    int c = t % AP;
    pre0[t] = (c < H2) ? fmaxf(b1[c], 0.f) : 0.f;
    if (c >= H2) pre1[t] = 0.f;
}

// ---------------------------------------------------------------------------
// Fused level step v5 (round-5 structure + 2-col phase C + fused proj/cls).
// 512 threads, TN=40 nodes, 250 blocks (~1 block/CU; LDS ~131 KB).
//  A: agg = gathered pre50 sums -> smA
//  B: p50 = relu(agg@WaT + deg*b2p + pb1) -> smP  (pads zeroed)
//  C: 200 threads x 2 adjacent cols (c=2t,2t+1), 2x52 weights in VGPRs,
//     broadcast LDS row reads shared by both cols -> Y  (halves LDS-pipe load
//     vs round-5's 400x1: per-CU DS pipe was 4x oversubscribed vs VALU)
//  GRU: per (n,o) from Y float4 (separate bulk phase — round-7 shfl fusion
//     regressed 3x; keep bulk-synchronous)
//  D: pre50_out = relu(nb1 + hs@nwT) ; E: coalesced state write
//  optional: xrOut (proj from hs) ; clsOut (classifier from hs)
// ---------------------------------------------------------------------------
__global__ __launch_bounds__(512) void k5_kernel(
    const float* __restrict__ preIn, float* __restrict__ preOut,
    const int* __restrict__ fedge, int srcbase,
    const int* __restrict__ boffs, const int* __restrict__ bdeg,
    const int* __restrict__ bnbr,
    const float* __restrict__ xrL,
    const float* __restrict__ WaT, const float* __restrict__ b2p,
    const float* __restrict__ pb1,
    const float* __restrict__ W4i, const float* __restrict__ b4i,
    const float* __restrict__ wi, const float* __restrict__ bi,
    const float* __restrict__ nwT, const float* __restrict__ nb1,
    float* __restrict__ state_out,
    const float* __restrict__ pw, const float* __restrict__ pbv,
    float* __restrict__ xrOut,
    const float* __restrict__ cw1, const float* __restrict__ cb1,
    const float* __restrict__ cw2, const float* __restrict__ cb2,
    float* __restrict__ clsOut)
{
    __shared__ float smA[TN * AP];     //  8.3 KB
    __shared__ float smP[TN * AP];     //  8.3 KB
    __shared__ float sWaT[H2 * AP];    // 10.4 KB
    __shared__ float sNwT[H2 * NWS];   // 21.6 KB
    __shared__ float Y[TN * YS];       // 64.6 KB (reused as cls scratch)
    __shared__ float hs[TN * HSS];     // 16.6 KB
    __shared__ float xs[TN * FD];
    __shared__ int sed[TN * KE];
    __shared__ int soff[TN];
    __shared__ int sdeg[TN];

    const int tid = threadIdx.x;
    const int nb = blockIdx.x * TN;

    // ---- per-thread 2-col weights (cols 2t, 2t+1; coalesced float2) ----
    float Wa_[AP], Wb_[AP];
    float b4a = 0.f, b4b = 0.f;
    float wxa0 = 0.f, wxa1 = 0.f, wxa2 = 0.f, wxa3 = 0.f;
    float wxb0 = 0.f, wxb1 = 0.f, wxb2 = 0.f, wxb3 = 0.f;
    if (tid < 200) {
#pragma unroll
        for (int k = 0; k < H2; ++k) {
            float2 wv = ((const float2*)(W4i + k * 400))[tid];
            Wa_[k] = wv.x; Wb_[k] = wv.y;
        }
        Wa_[50] = 0.f; Wa_[51] = 0.f; Wb_[50] = 0.f; Wb_[51] = 0.f;
        float2 bv = ((const float2*)b4i)[tid];
        b4a = bv.x; b4b = bv.y;
        int o2 = tid >> 1;
        if ((tid & 1) == 0) {   // cols (4o,4o+1): col B is gate r -> wi rows o
            wxb0 = wi[o2 * 4 + 0]; wxb1 = wi[o2 * 4 + 1];
            wxb2 = wi[o2 * 4 + 2]; wxb3 = wi[o2 * 4 + 3];
        } else {                // cols (4o+2,4o+3): col A is gate z -> wi rows 100+o
            wxa0 = wi[(100 + o2) * 4 + 0]; wxa1 = wi[(100 + o2) * 4 + 1];
            wxa2 = wi[(100 + o2) * 4 + 2]; wxa3 = wi[(100 + o2) * 4 + 3];
        }
    }
    // LDS staging (active direction only)
    for (int idx = tid; idx < H2 * AP / 4; idx += 512)
        ((float4*)sWaT)[idx] = ((const float4*)WaT)[idx];
    for (int idx = tid; idx < H2 * NWS / 4; idx += 512)
        ((float4*)sNwT)[idx] = ((const float4*)nwT)[idx];
    if (tid < TN)
        ((float4*)xs)[tid] = ((const float4*)xrL)[nb + tid];
    if (fedge) {
        if (tid < TN * KE) sed[tid] = fedge[nb * KE + tid] - srcbase;
    } else {
        if (tid < TN) { soff[tid] = boffs[nb + tid]; sdeg[tid] = bdeg[nb + tid]; }
    }
    __syncthreads();

    // ---- A: gather + sum pre50 rows -> smA ----
    const float4* pre4 = (const float4*)preIn;
    for (int idx = tid; idx < TN * 13; idx += 512) {
        int n = idx / 13, q = idx - n * 13;
        float4 a = make_float4(0.f, 0.f, 0.f, 0.f);
        if (fedge) {
#pragma unroll
            for (int e = 0; e < KE; ++e) {
                int rr = sed[KE * n + e];
                float4 v = pre4[rr * 13 + q];
                a.x += v.x; a.y += v.y; a.z += v.z; a.w += v.w;
            }
        } else {
            int off = soff[n], d = sdeg[n];
            for (int e = 0; e < d; ++e) {
                int rr = bnbr[off + e];
                float4 v = pre4[rr * 13 + q];
                a.x += v.x; a.y += v.y; a.z += v.z; a.w += v.w;
            }
        }
        *(float4*)&smA[n * AP + 4 * q] = a;
    }
    __syncthreads();

    // ---- B: p50 -> smP (+ zero pads 50,51) ----
    for (int idx = tid; idx < TN * H2; idx += 512) {
        int n = idx / H2, cc = idx - n * H2;
        float dgv = fedge ? 3.0f : (float)sdeg[n];
        float acc = pb1[cc] + dgv * b2p[cc];
        const float4* ar = (const float4*)&smA[n * AP];
        const float4* wr = (const float4*)&sWaT[cc * AP];
#pragma unroll
        for (int q = 0; q < 13; ++q) {
            float4 av = ar[q], wv = wr[q];
            acc = fmaf(av.x, wv.x, acc); acc = fmaf(av.y, wv.y, acc);
            acc = fmaf(av.z, wv.z, acc); acc = fmaf(av.w, wv.w, acc);
        }
        smP[n * AP + cc] = fmaxf(acc, 0.f);
    }
    if (tid < TN) { smP[tid * AP + 50] = 0.f; smP[tid * AP + 51] = 0.f; }
    __syncthreads();

    // ---- C: Y[n][2t..2t+1] = b4 + P@W4i + xs@wx  (row broadcast shared) ----
    if (tid < 200) {
        for (int n = 0; n < TN; ++n) {
            const float4* pr = (const float4*)&smP[n * AP];
            float a = b4a, b = b4b;
#pragma unroll
            for (int q = 0; q < 13; ++q) {
                float4 pv = pr[q];
                a = fmaf(pv.x, Wa_[4 * q + 0], a); b = fmaf(pv.x, Wb_[4 * q + 0], b);
                a = fmaf(pv.y, Wa_[4 * q + 1], a); b = fmaf(pv.y, Wb_[4 * q + 1], b);
                a = fmaf(pv.z, Wa_[4 * q + 2], a); b = fmaf(pv.z, Wb_[4 * q + 2], b);
                a = fmaf(pv.w, Wa_[4 * q + 3], a); b = fmaf(pv.w, Wb_[4 * q + 3], b);
            }
            float4 xv = *(const float4*)&xs[n * FD];
            a = fmaf(xv.x, wxa0, a); a = fmaf(xv.y, wxa1, a);
            a = fmaf(xv.z, wxa2, a); a = fmaf(xv.w, wxa3, a);
            b = fmaf(xv.x, wxb0, b); b = fmaf(xv.y, wxb1, b);
            b = fmaf(xv.z, wxb2, b); b = fmaf(xv.w, wxb3, b);
            *(float2*)&Y[n * YS + 2 * tid] = make_float2(a, b);
        }
    }
    __syncthreads();

    // ---- GRU: per (n,o); bulk phase reading Y float4 ----
    {
        int w8 = tid >> 6;
        int n = tid & 63;
        if (n < TN) {
            float4 xv = *(const float4*)&xs[n * FD];
            for (int o = w8; o < H; o += 8) {
                float4 yv = *(const float4*)&Y[n * YS + 4 * o];
                float inn = bi[200 + o] + xv.x * wi[(200 + o) * 4 + 0]
                                        + xv.y * wi[(200 + o) * 4 + 1]
                                        + xv.z * wi[(200 + o) * 4 + 2]
                                        + xv.w * wi[(200 + o) * 4 + 3];
                float r = sigmoidf_(yv.y);
                float z = sigmoidf_(yv.z);
                float t = tanhf_(inn + r * yv.w);
                hs[n * HSS + o] = fmaf(z, yv.x - t, t);   // (1-z)t + z*m
            }
        }
    }
    __syncthreads();   // hs ready; Y dead (reusable)

    // ---- D: next step's pre50 ----
    for (int idx = tid; idx < TN * H2; idx += 512) {
        int n = idx / H2, cc = idx - n * H2;
        float acc = nb1[cc];
        const float4* hr = (const float4*)&hs[n * HSS];
        const float4* wr = (const float4*)&sNwT[cc * NWS];
#pragma unroll
        for (int q = 0; q < 25; ++q) {
            float4 hv = hr[q], wv = wr[q];
            acc = fmaf(hv.x, wv.x, acc); acc = fmaf(hv.y, wv.y, acc);
            acc = fmaf(hv.z, wv.z, acc); acc = fmaf(hv.w, wv.w, acc);
        }
        preOut[(size_t)(nb + n) * AP + cc] = fmaxf(acc, 0.f);
    }
    // ---- E: coalesced state write ----
    for (int idx = tid; idx < TN * H; idx += 512) {
        int n = idx / H, cc = idx - n * H;
        state_out[(size_t)(nb + n) * H + cc] = hs[n * HSS + cc];
    }
    // ---- fused proj (round-0 tail): xr[level] from hs ----
    if (xrOut) {
        for (int idx = tid; idx < TN * FD; idx += 512) {
            int n = idx >> 2, f = idx & 3;
            float acc = pbv[f];
            for (int i = 0; i < H; ++i)
                acc = fmaf(hs[n * HSS + i], pw[i * FD + f], acc);
            xrOut[(size_t)(nb + n) * FD + f] = acc;
        }
    }
    // ---- fused cls (final step only): pred[0..NPL) from hs ----
    if (clsOut) {
        for (int idx = tid; idx < TN * DM; idx += 512) {
            int n = idx / DM, j = idx - n * DM;
            float acc = cb1[j];
            for (int i = 0; i < H; ++i)
                acc = fmaf(hs[n * HSS + i], cw1[i * DM + j], acc);
            Y[n * 32 + j] = acc;   // reuse Y as scratch
        }
        __syncthreads();
        if (tid < TN) {
            float v = cb2[0];
#pragma unroll
            for (int j = 0; j < DM; ++j)
                v = fmaf(fmaxf(Y[tid * 32 + j], 0.f), cw2[j], v);
            clsOut[nb + tid] = sigmoidf_(v);
        }
    }
}

// ---------------------------------------------------------------------------
// Single-block gate sweep: 11 serially-dependent levels with __syncthreads as
// the level barrier (global writes within one block are visible after
// __syncthreads). Replaces 11 launches + copy.
// ---------------------------------------------------------------------------
__global__ __launch_bounds__(1024) void gates_kernel(
    const float* __restrict__ x, const int* __restrict__ src,
    float* __restrict__ pred, float* __restrict__ out)
{
    for (int l = 1; l < NLV; ++l) {
        for (int j = threadIdx.x; j < NPL; j += 1024) {
            int e0 = (l - 1) * EPL + KE * j;
            int dg = l * NPL + j;
            float v0 = pred[src[e0 + 0]];
            float v1 = pred[src[e0 + 1]];
            float v2 = pred[src[e0 + 2]];
            const float invT = 100.0f;
            float mx = fmaxf(v0, fmaxf(v1, v2));
            float e0x = __expf((v0 - mx) * invT);
            float e1x = __expf((v1 - mx) * invT);
            float e2x = __expf((v2 - mx) * invT);
            float smax = (e0x * v0 + e1x * v1 + e2x * v2) / (e0x + e1x + e2x);
            float mn = fminf(v0, fminf(v1, v2));
            float f0 = __expf((mn - v0) * invT);
            float f1 = __expf((mn - v1) * invT);
            float f2 = __expf((mn - v2) * invT);
            float smin = (f0 * v0 + f1 * v1 + f2 * v2) / (f0 + f1 + f2);
            float am = x[(size_t)dg * FD + 1];
            float om = x[(size_t)dg * FD + 2];
            float nm = x[(size_t)dg * FD + 3];
            pred[dg] = am * smin + om * smax + nm * (3.f - (v0 + v1 + v2));
        }
        __syncthreads();
    }
    for (int j = threadIdx.x; j < NPL; j += 1024)
        out[j] = pred[(NLV - 1) * NPL + j];
}

// ---------------------------------------------------------------------------
extern "C" void kernel_launch(void* const* d_in, const int* in_sizes, int n_in,
                              void* d_out, int out_size, void* d_ws, size_t ws_size,
                              hipStream_t stream)
{
    const float* x        = (const float*)d_in[0];
    const float* fpre_w1  = (const float*)d_in[1];
    const float* fpre_b1  = (const float*)d_in[2];
    const float* fpre_w2  = (const float*)d_in[3];
    const float* fpre_b2  = (const float*)d_in[4];
    const float* fpost_w1 = (const float*)d_in[5];
    const float* fpost_b1 = (const float*)d_in[6];
    const float* fpost_w2 = (const float*)d_in[7];
    const float* fpost_b2 = (const float*)d_in[8];
    const float* bpre_w1  = (const float*)d_in[9];
    const float* bpre_b1  = (const float*)d_in[10];
    const float* bpre_w2  = (const float*)d_in[11];
    const float* bpre_b2  = (const float*)d_in[12];
    const float* bpost_w1 = (const float*)d_in[13];
    const float* bpost_b1 = (const float*)d_in[14];
    const float* bpost_w2 = (const float*)d_in[15];
    const float* bpost_b2 = (const float*)d_in[16];
    const float* gruf_wi  = (const float*)d_in[17];
    const float* gruf_wh  = (const float*)d_in[18];
    const float* gruf_bi  = (const float*)d_in[19];
    const float* gruf_bh  = (const float*)d_in[20];
    const float* grub_wi  = (const float*)d_in[21];
    const float* grub_wh  = (const float*)d_in[22];
    const float* grub_bi  = (const float*)d_in[23];
    const float* grub_bh  = (const float*)d_in[24];
    const float* proj_w   = (const float*)d_in[25];
    const float* proj_b   = (const float*)d_in[26];
    const float* cls_w1   = (const float*)d_in[27];
    const float* cls_b1   = (const float*)d_in[28];
    const float* cls_w2   = (const float*)d_in[29];
    const float* cls_b2   = (const float*)d_in[30];
    const int*   src      = (const int*)d_in[31];
    const int*   dst      = (const int*)d_in[32];
    float* out = (float*)d_out;

    size_t off = 0;
    auto carve = [&](size_t nbytes) -> void* {
        void* ptr = (char*)d_ws + off;
        off += (nbytes + 255) & ~(size_t)255;
        return ptr;
    };
    float* state = (float*)carve((size_t)NT * H * 4);
    float* xr    = (float*)carve((size_t)NT * FD * 4);
    float* pred  = (float*)carve((size_t)NT * 4);
    float* pre0  = (float*)carve((size_t)NPL * AP * 4);
    float* pre1  = (float*)carve((size_t)NPL * AP * 4);
    int*   counts= (int*)carve((size_t)11 * NPL * 4);
    int*   cursor= (int*)carve((size_t)11 * NPL * 4);
    int*   offs  = (int*)carve((size_t)11 * NPL * 4);
    int*   nbrb  = (int*)carve((size_t)NE * 4);
    float* WaTF  = (float*)carve(H2 * AP * 4);
    float* b2pF  = (float*)carve(64 * 4);
    float* W4iF  = (float*)carve(H2 * 400 * 4);
    float* b4iF  = (float*)carve(400 * 4);
    float* nwTF  = (float*)carve(H2 * NWS * 4);
    float* WaTB  = (float*)carve(H2 * AP * 4);
    float* b2pB  = (float*)carve(64 * 4);
    float* W4iB  = (float*)carve(H2 * 400 * 4);
    float* b4iB  = (float*)carve(400 * 4);
    float* nwTB  = (float*)carve(H2 * NWS * 4);

    // zero counts AND cursor including alignment padding between them
    hipMemsetAsync(counts, 0, (size_t)((char*)offs - (char*)counts), stream);

    fold_kernel<<<(2 * 28350 + 255) / 256, 256, 0, stream>>>(
        fpre_w2, fpre_b2, fpost_w1, fpost_w2, fpost_b2, gruf_wh, gruf_bh, gruf_bi, fpre_w1,
        bpre_w2, bpre_b2, bpost_w1, bpost_w2, bpost_b2, grub_wh, grub_bh, grub_bi, bpre_w1,
        WaTF, b2pF, W4iF, b4iF, nwTF,
        WaTB, b2pB, W4iB, b4iB, nwTB);
    csr_count<<<(NE + 255) / 256, 256, 0, stream>>>(src, counts);
    csr_scan<<<11, 256, 0, stream>>>(counts, offs);
    csr_fill<<<(NE + 255) / 256, 256, 0, stream>>>(src, dst, offs, cursor, nbrb);
    pre_init<<<(NPL * AP + 255) / 256, 256, 0, stream>>>(fpre_b1, pre0, pre1);

    float* preBuf[2] = { pre0, pre1 };
    int pb = 0;
    const int k5Grid = NPL / TN;   // 250

    for (int r = 0; r < 2; ++r) {
        const float* xr_use = (r == 0) ? x : xr;
        // forward levels 1..11
        for (int l = 1; l < NLV; ++l) {
            bool lastf = (l == NLV - 1);
            float* xrOut = (r == 0 && lastf) ? xr + (size_t)l * NPL * FD : nullptr;
            k5_kernel<<<k5Grid, 512, 0, stream>>>(
                preBuf[pb], preBuf[pb ^ 1],
                src + (size_t)(l - 1) * EPL, (l - 1) * NPL,
                nullptr, nullptr, nullptr,
                xr_use + (size_t)l * NPL * FD,
                WaTF, b2pF, fpost_b1, W4iF, b4iF, gruf_wi, gruf_bi,
                lastf ? nwTB : nwTF, lastf ? bpre_b1 : fpre_b1,
                state + (size_t)l * NPL * H,
                proj_w, proj_b, xrOut,
                cls_w1, cls_b1, cls_w2, cls_b2, nullptr);
            pb ^= 1;
        }
        // backward levels 10..0
        for (int f = NLV - 2; f >= 0; --f) {
            bool lastb = (f == 0);
            float* xrOut = (r == 0) ? xr + (size_t)f * NPL * FD : nullptr;
            float* clsOut = (r == 1 && lastb) ? pred : nullptr;
            k5_kernel<<<k5Grid, 512, 0, stream>>>(
                preBuf[pb], preBuf[pb ^ 1],
                nullptr, 0,
                offs + (size_t)f * NPL, counts + (size_t)f * NPL, nbrb + (size_t)f * EPL,
                xr_use + (size_t)f * NPL * FD,
                WaTB, b2pB, bpost_b1, W4iB, b4iB, grub_wi, grub_bi,
                lastb ? nwTF : nwTB, lastb ? fpre_b1 : bpre_b1,
                state + (size_t)f * NPL * H,
                proj_w, proj_b, xrOut,
                cls_w1, cls_b1, cls_w2, cls_b2, clsOut);
            pb ^= 1;
        }
    }

    gates_kernel<<<1, 1024, 0, stream>>>(x, src, pred, out);
}

// Round 9
// 1719.245 us; speedup vs baseline: 1.5059x; 1.5059x over previous
//
#include <hip/hip_runtime.h>
#include <cstdint>
#include <cstddef>

#define NLV 12
#define NPL 10000
#define KE 3
#define EPL (NPL * KE)   // 30000 edges per level block
#define NE (11 * EPL)    // 330000
#define NT (NLV * NPL)   // 120000 nodes
#define H 100
#define H2 50
#define FD 4
#define DM 30
#define AP 52            // pre50 row stride (13 float4)
#define TN 40            // nodes per block (250 blocks exactly)
#define YS 404           // Y LDS row stride (dwords)
#define HSS 104          // hs LDS row stride
#define NWS 108          // nwT row stride

__device__ __forceinline__ float sigmoidf_(float x) {
    return 1.0f / (1.0f + __expf(-x));
}
__device__ __forceinline__ float tanhf_(float x) {
    float e = __expf(2.0f * x);
    return 1.0f - 2.0f / (e + 1.0f);
}

// ---------------------------------------------------------------------------
// Weight folding per direction (PER = 28350 outputs):
//  WaT[c*52+k] = (w2@pw1)[k][c] ;  b2p[c] = (b2@pw1)[c]
//  W4i[k*400+c]  c=4o+g, k<50:  g0: pw2[k][o]; g1..3: sum_m pw2[k][m]*wh[(g-1)*100+o][m]
//  b4i[c]: g0: pb2[o]; g1: bh[o]+fold+bi[o]; g2: bh[100+o]+fold+bi[100+o]; g3: bh[200+o]+fold
//  nwT[c*108+k] = (k<100) ? w1pre[k*50+c] : 0
// ---------------------------------------------------------------------------
__global__ void fold_kernel(
    const float* __restrict__ w2F, const float* __restrict__ b2F_,
    const float* __restrict__ pw1F, const float* __restrict__ pw2F,
    const float* __restrict__ pb2F, const float* __restrict__ whF,
    const float* __restrict__ bhF, const float* __restrict__ biF,
    const float* __restrict__ w1pF,
    const float* __restrict__ w2B, const float* __restrict__ b2B_,
    const float* __restrict__ pw1B, const float* __restrict__ pw2B,
    const float* __restrict__ pb2B, const float* __restrict__ whB,
    const float* __restrict__ bhB, const float* __restrict__ biB,
    const float* __restrict__ w1pB,
    float* __restrict__ WaTF, float* __restrict__ b2pF,
    float* __restrict__ W4iF, float* __restrict__ b4iF, float* __restrict__ nwTF,
    float* __restrict__ WaTB, float* __restrict__ b2pB,
    float* __restrict__ W4iB, float* __restrict__ b4iB, float* __restrict__ nwTB)
{
    const int PER = 28350;
    int gid = blockIdx.x * blockDim.x + threadIdx.x;
    if (gid >= 2 * PER) return;
    int dir = gid / PER;
    int i = gid - dir * PER;
    const float* w2  = dir ? w2B  : w2F;
    const float* b2  = dir ? b2B_ : b2F_;
    const float* pw1 = dir ? pw1B : pw1F;
    const float* pw2 = dir ? pw2B : pw2F;
    const float* wh  = dir ? whB  : whF;
    const float* bh  = dir ? bhB  : bhF;
    const float* bi  = dir ? biB  : biF;
    const float* pb2 = dir ? pb2B : pb2F;
    const float* w1p = dir ? w1pB : w1pF;
    float* WaT = dir ? WaTB : WaTF;
    float* b2p = dir ? b2pB : b2pF;
    float* W4i = dir ? W4iB : W4iF;
    float* b4i = dir ? b4iB : b4iF;
    float* nwT = dir ? nwTB : nwTF;

    if (i < 2500) {
        int c = i / 50, k = i - c * 50;
        float s = 0.f;
        for (int m = 0; m < 100; ++m) s += w2[k * 100 + m] * pw1[m * 50 + c];
        WaT[c * AP + k] = s;
    } else if (i < 2550) {
        int c = i - 2500;
        float s = 0.f;
        for (int m = 0; m < 100; ++m) s += b2[m] * pw1[m * 50 + c];
        b2p[c] = s;
    } else if (i < 22550) {
        int j = i - 2550;
        int k = j / 400, c = j - k * 400;
        int o = c >> 2, g = c & 3;
        float s;
        if (g == 0) {
            s = pw2[k * 100 + o];
        } else {
            int row = (g - 1) * 100 + o;
            s = 0.f;
            for (int m = 0; m < 100; ++m) s += pw2[k * 100 + m] * wh[row * 100 + m];
        }
        W4i[k * 400 + c] = s;
    } else if (i < 22950) {
        int c = i - 22550;
        int o = c >> 2, g = c & 3;
        float s;
        if (g == 0) {
            s = pb2[o];
        } else {
            int row = (g - 1) * 100 + o;
            s = bh[row];
            for (int m = 0; m < 100; ++m) s += pb2[m] * wh[row * 100 + m];
            if (g == 1) s += bi[o];
            else if (g == 2) s += bi[100 + o];
        }
        b4i[c] = s;
    } else {
        int j = i - 22950;
        int c = j / NWS, k = j - c * NWS;
        nwT[c * NWS + k] = (k < 100) ? w1p[k * 50 + c] : 0.f;
    }
}

// ---------------------------------------------------------------------------
// CSR build (once): group level-f edges by src; store LOCAL dst index.
// counts doubles as per-node in-degree.
// ---------------------------------------------------------------------------
__global__ void csr_count(const int* __restrict__ src, int* __restrict__ counts)
{
    int e = blockIdx.x * blockDim.x + threadIdx.x;
    if (e >= NE) return;
    int f = e / EPL;
    int sl = src[e] - f * NPL;
    atomicAdd(&counts[f * NPL + sl], 1);
}

__global__ void csr_scan(const int* __restrict__ counts, int* __restrict__ offs)
{
    int f = blockIdx.x;
    int t = threadIdx.x;
    const int base = f * NPL;
    const int CH = 40;
    __shared__ int part[256];
    int s = 0;
    for (int k = 0; k < CH; ++k) {
        int idx = t * CH + k;
        if (idx < NPL) s += counts[base + idx];
    }
    part[t] = s;
    __syncthreads();
    if (t == 0) {
        int run = 0;
        for (int j = 0; j < 256; ++j) { int tmp = part[j]; part[j] = run; run += tmp; }
    }
    __syncthreads();
    int run = part[t];
    for (int k = 0; k < CH; ++k) {
        int idx = t * CH + k;
        if (idx < NPL) { offs[base + idx] = run; run += counts[base + idx]; }
    }
}

__global__ void csr_fill(const int* __restrict__ src, const int* __restrict__ dst,
                         const int* __restrict__ offs, int* __restrict__ cursor,
                         int* __restrict__ nbrb)
{
    int e = blockIdx.x * blockDim.x + threadIdx.x;
    if (e >= NE) return;
    int f = e / EPL;
    int sl = src[e] - f * NPL;
    int p = atomicAdd(&cursor[f * NPL + sl], 1);
    nbrb[f * EPL + offs[f * NPL + sl] + p] = dst[e] - (f + 1) * NPL;
}

// pre0 = relu(b1) broadcast (+zero pads); pre1 pads zeroed
__global__ void pre_init(const float* __restrict__ b1,
                         float* __restrict__ pre0, float* __restrict__ pre1)
{
    int t = blockIdx.x * blockDim.x + threadIdx.x;
    if (t >= NPL * AP) return;
    int c = t % AP;
    pre0[t] = (c < H2) ? fmaxf(b1[c], 0.f) : 0.f;
    if (c >= H2) pre1[t] = 0.f;
}

// ---------------------------------------------------------------------------
// Fused level step (round-5 structure, measured 592 us total; UB fixed).
// 512 threads, TN=40 nodes/block, 250 blocks.
// Thread c<400 owns output col c=4o+g with 52 weights in VGPRs (pads zero).
//  A: gather pre50 rows -> smA
//  B: p50 = relu(agg@WaT + deg*b2p + pb1) -> smP  (pads [50,51] zeroed)
//  C: Y[n][c] = b4i[c] + smP[n]·Wc + xs[n]·wx   (gi folded for r,z)
//  GRU: bulk phase per (n,o): r=sig(Y1) z=sig(Y2) t=tanh(inn+r*Y3) -> hs
//  D: pre50_out = relu(nb1 + hs@nwT)
//  E: coalesced state write
// (Round-7/8 variants — shfl-fused GRU, 2-col C — both measured slower;
//  keep this bulk-synchronous 400x1 layout.)
// ---------------------------------------------------------------------------
__global__ __launch_bounds__(512) void k3_kernel(
    const float* __restrict__ preIn, float* __restrict__ preOut,
    const int* __restrict__ fedge, int srcbase,
    const int* __restrict__ boffs, const int* __restrict__ bdeg,
    const int* __restrict__ bnbr,
    const float* __restrict__ xrL,
    const float* __restrict__ WaT, const float* __restrict__ b2p,
    const float* __restrict__ pb1,
    const float* __restrict__ W4i, const float* __restrict__ b4i,
    const float* __restrict__ wi, const float* __restrict__ bi,
    const float* __restrict__ nwT, const float* __restrict__ nb1,
    float* __restrict__ state_out)
{
    __shared__ float smA[TN * AP];     //  8.3 KB
    __shared__ float smP[TN * AP];     //  8.3 KB
    __shared__ float sWaT[H2 * AP];    // 10.4 KB
    __shared__ float sNwT[H2 * NWS];   // 21.6 KB
    __shared__ float Y[TN * YS];       // 64.6 KB
    __shared__ float hs[TN * HSS];     // 16.6 KB
    __shared__ float xs[TN * FD];
    __shared__ int sed[TN * KE];
    __shared__ int soff[TN];
    __shared__ int sdeg[TN];

    int tid = threadIdx.x;
    int nb = blockIdx.x * TN;
    int c = tid;                       // output col for phase C
    int g = c & 3, o4 = c >> 2;

    // ---- stage: per-thread weights (global, coalesced rows) ----
    float Wc[AP];                      // 52 entries; [50,51] zero (round-5 OOB fix)
    float b4c = 0.f, wx0 = 0.f, wx1 = 0.f, wx2 = 0.f, wx3 = 0.f;
    if (c < 400) {
#pragma unroll
        for (int k = 0; k < H2; ++k) Wc[k] = W4i[k * 400 + c];
        Wc[50] = 0.f; Wc[51] = 0.f;
        b4c = b4i[c];
        if (g == 1 || g == 2) {
            int off = ((g == 1) ? o4 : (100 + o4)) * 4;
            wx0 = wi[off + 0]; wx1 = wi[off + 1]; wx2 = wi[off + 2]; wx3 = wi[off + 3];
        }
    }
    // LDS staging: WaT, nwT, xs, edge metadata
    for (int idx = tid; idx < H2 * AP / 4; idx += 512)
        ((float4*)sWaT)[idx] = ((const float4*)WaT)[idx];
    for (int idx = tid; idx < H2 * NWS / 4; idx += 512)
        ((float4*)sNwT)[idx] = ((const float4*)nwT)[idx];
    if (tid < TN)
        ((float4*)xs)[tid] = ((const float4*)xrL)[nb + tid];
    if (fedge) {
        if (tid < TN * KE) sed[tid] = fedge[nb * KE + tid] - srcbase;
    } else {
        if (tid < TN) { soff[tid] = boffs[nb + tid]; sdeg[tid] = bdeg[nb + tid]; }
    }
    __syncthreads();

    // ---- phase A: gather + sum pre50 rows -> smA ----
    const float4* pre4 = (const float4*)preIn;
    for (int idx = tid; idx < TN * 13; idx += 512) {
        int n = idx / 13, q = idx - n * 13;
        float4 a = make_float4(0.f, 0.f, 0.f, 0.f);
        if (fedge) {
#pragma unroll
            for (int e = 0; e < KE; ++e) {
                int r = sed[KE * n + e];
                float4 v = pre4[r * 13 + q];
                a.x += v.x; a.y += v.y; a.z += v.z; a.w += v.w;
            }
        } else {
            int off = soff[n], d = sdeg[n];
            for (int e = 0; e < d; ++e) {
                int r = bnbr[off + e];
                float4 v = pre4[r * 13 + q];
                a.x += v.x; a.y += v.y; a.z += v.z; a.w += v.w;
            }
        }
        *(float4*)&smA[n * AP + 4 * q] = a;
    }
    __syncthreads();

    // ---- phase B: p50 -> smP (+ zero pads 50,51 — round-5 uninit-LDS fix) ----
    for (int idx = tid; idx < TN * H2; idx += 512) {
        int n = idx / H2, cc = idx - n * H2;
        float dgv = fedge ? 3.0f : (float)sdeg[n];
        float acc = pb1[cc] + dgv * b2p[cc];
        const float4* ar = (const float4*)&smA[n * AP];
        const float4* wr = (const float4*)&sWaT[cc * AP];
#pragma unroll
        for (int q = 0; q < 13; ++q) {
            float4 av = ar[q], wv = wr[q];
            acc = fmaf(av.x, wv.x, acc); acc = fmaf(av.y, wv.y, acc);
            acc = fmaf(av.z, wv.z, acc); acc = fmaf(av.w, wv.w, acc);
        }
        smP[n * AP + cc] = fmaxf(acc, 0.f);
    }
    if (tid < TN) { smP[tid * AP + 50] = 0.f; smP[tid * AP + 51] = 0.f; }
    __syncthreads();

    // ---- phase C: Y = b4 + P@W4i + xs@wx ----
    if (c < 400) {
#pragma unroll 2
        for (int n = 0; n < TN; ++n) {
            const float4* pr = (const float4*)&smP[n * AP];
            float acc = b4c;
#pragma unroll
            for (int q = 0; q < 13; ++q) {
                float4 pv = pr[q];
                acc = fmaf(pv.x, Wc[4 * q + 0], acc);
                acc = fmaf(pv.y, Wc[4 * q + 1], acc);
                acc = fmaf(pv.z, Wc[4 * q + 2], acc);
                acc = fmaf(pv.w, Wc[4 * q + 3], acc);
            }
            float4 xv = *(const float4*)&xs[n * FD];
            acc = fmaf(xv.x, wx0, acc); acc = fmaf(xv.y, wx1, acc);
            acc = fmaf(xv.z, wx2, acc); acc = fmaf(xv.w, wx3, acc);
            Y[n * YS + c] = acc;
        }
    }
    __syncthreads();

    // ---- GRU: per (n,o); o wave-uniform -> wi/bi via s_load ----
    {
        int w8 = __builtin_amdgcn_readfirstlane(tid >> 6);
        int n = tid & 63;
        if (n < TN) {
            float4 xv = *(const float4*)&xs[n * FD];
            for (int o = w8; o < H; o += 8) {
                float4 yv = *(const float4*)&Y[n * YS + 4 * o];
                float inn = bi[200 + o] + xv.x * wi[(200 + o) * 4 + 0]
                                        + xv.y * wi[(200 + o) * 4 + 1]
                                        + xv.z * wi[(200 + o) * 4 + 2]
                                        + xv.w * wi[(200 + o) * 4 + 3];
                float r = sigmoidf_(yv.y);
                float z = sigmoidf_(yv.z);
                float t = tanhf_(inn + r * yv.w);
                hs[n * HSS + o] = fmaf(z, yv.x - t, t);   // (1-z)t + z*m
            }
        }
    }
    __syncthreads();

    // ---- phase D: next step's pre50 ----
    for (int idx = tid; idx < TN * H2; idx += 512) {
        int n = idx / H2, cc = idx - n * H2;
        float acc = nb1[cc];
        const float4* hr = (const float4*)&hs[n * HSS];
        const float4* wr = (const float4*)&sNwT[cc * NWS];
#pragma unroll
        for (int q = 0; q < 25; ++q) {
            float4 hv = hr[q], wv = wr[q];
            acc = fmaf(hv.x, wv.x, acc); acc = fmaf(hv.y, wv.y, acc);
            acc = fmaf(hv.z, wv.z, acc); acc = fmaf(hv.w, wv.w, acc);
        }
        preOut[(size_t)(nb + n) * AP + cc] = fmaxf(acc, 0.f);
    }

    // ---- phase E: coalesced state write ----
    for (int idx = tid; idx < TN * H; idx += 512) {
        int n = idx / H, cc = idx - n * H;
        state_out[(size_t)(nb + n) * H + cc] = hs[n * HSS + cc];
    }
}

// ---------------------------------------------------------------------------
// xr = state @ proj_w + proj_b ; thread = (node, f)
// ---------------------------------------------------------------------------
__global__ __launch_bounds__(256) void proj_kernel(
    const float* __restrict__ state, const float* __restrict__ pw,
    const float* __restrict__ pb, float* __restrict__ xr)
{
    int t = blockIdx.x * 256 + threadIdx.x;
    if (t >= NT * FD) return;
    int node = t >> 2, f = t & 3;
    const float4* rp = (const float4*)(state + (size_t)node * H);
    float acc = pb[f];
    for (int i4 = 0; i4 < 25; ++i4) {
        float4 v = rp[i4];
        acc = fmaf(v.x, pw[(4 * i4 + 0) * 4 + f], acc);
        acc = fmaf(v.y, pw[(4 * i4 + 1) * 4 + f], acc);
        acc = fmaf(v.z, pw[(4 * i4 + 2) * 4 + f], acc);
        acc = fmaf(v.w, pw[(4 * i4 + 3) * 4 + f], acc);
    }
    xr[t] = acc;
}

// ---------------------------------------------------------------------------
// Classification on level-0 nodes only
// ---------------------------------------------------------------------------
__global__ void cls_kernel(const float* __restrict__ state,
                           const float* __restrict__ w1, const float* __restrict__ b1,
                           const float* __restrict__ w2, const float* __restrict__ b2,
                           float* __restrict__ pred)
{
    int n = blockIdx.x * blockDim.x + threadIdx.x;
    if (n >= NPL) return;
    float h[DM];
#pragma unroll
    for (int j = 0; j < DM; ++j) h[j] = b1[j];
    const float* sp = state + (size_t)n * H;
    for (int i = 0; i < H; ++i) {
        float s = sp[i];
#pragma unroll
        for (int j = 0; j < DM; ++j) h[j] = fmaf(s, w1[i * DM + j], h[j]);
    }
    float v = b2[0];
#pragma unroll
    for (int j = 0; j < DM; ++j) v = fmaf(fmaxf(h[j], 0.f), w2[j], v);
    pred[n] = sigmoidf_(v);
}

// ---------------------------------------------------------------------------
// Hard gate evaluation, one level per launch (round-8 single-block version
// measured 253 us — latency-bound on 1 CU; multi-launch is 5x faster).
// Final level (l==NLV-1) also writes `out` directly (saves copy launch).
// ---------------------------------------------------------------------------
__global__ void gate_kernel(const float* __restrict__ x, const int* __restrict__ src,
                            float* __restrict__ pred, int l, float* __restrict__ out)
{
    int j = blockIdx.x * blockDim.x + threadIdx.x;
    if (j >= NPL) return;
    int e0 = (l - 1) * EPL + KE * j;
    int dg = l * NPL + j;
    float v0 = pred[src[e0 + 0]];
    float v1 = pred[src[e0 + 1]];
    float v2 = pred[src[e0 + 2]];
    const float invT = 100.0f;
    float mx = fmaxf(v0, fmaxf(v1, v2));
    float e0x = __expf((v0 - mx) * invT);
    float e1x = __expf((v1 - mx) * invT);
    float e2x = __expf((v2 - mx) * invT);
    float smax = (e0x * v0 + e1x * v1 + e2x * v2) / (e0x + e1x + e2x);
    float mn = fminf(v0, fminf(v1, v2));
    float f0 = __expf((mn - v0) * invT);
    float f1 = __expf((mn - v1) * invT);
    float f2 = __expf((mn - v2) * invT);
    float smin = (f0 * v0 + f1 * v1 + f2 * v2) / (f0 + f1 + f2);
    float am = x[(size_t)dg * FD + 1];
    float om = x[(size_t)dg * FD + 2];
    float nm = x[(size_t)dg * FD + 3];
    float v = am * smin + om * smax + nm * (3.f - (v0 + v1 + v2));
    pred[dg] = v;
    if (out) out[j] = v;
}

// ---------------------------------------------------------------------------
extern "C" void kernel_launch(void* const* d_in, const int* in_sizes, int n_in,
                              void* d_out, int out_size, void* d_ws, size_t ws_size,
                              hipStream_t stream)
{
    const float* x        = (const float*)d_in[0];
    const float* fpre_w1  = (const float*)d_in[1];
    const float* fpre_b1  = (const float*)d_in[2];
    const float* fpre_w2  = (const float*)d_in[3];
    const float* fpre_b2  = (const float*)d_in[4];
    const float* fpost_w1 = (const float*)d_in[5];
    const float* fpost_b1 = (const float*)d_in[6];
    const float* fpost_w2 = (const float*)d_in[7];
    const float* fpost_b2 = (const float*)d_in[8];
    const float* bpre_w1  = (const float*)d_in[9];
    const float* bpre_b1  = (const float*)d_in[10];
    const float* bpre_w2  = (const float*)d_in[11];
    const float* bpre_b2  = (const float*)d_in[12];
    const float* bpost_w1 = (const float*)d_in[13];
    const float* bpost_b1 = (const float*)d_in[14];
    const float* bpost_w2 = (const float*)d_in[15];
    const float* bpost_b2 = (const float*)d_in[16];
    const float* gruf_wi  = (const float*)d_in[17];
    const float* gruf_wh  = (const float*)d_in[18];
    const float* gruf_bi  = (const float*)d_in[19];
    const float* gruf_bh  = (const float*)d_in[20];
    const float* grub_wi  = (const float*)d_in[21];
    const float* grub_wh  = (const float*)d_in[22];
    const float* grub_bi  = (const float*)d_in[23];
    const float* grub_bh  = (const float*)d_in[24];
    const float* proj_w   = (const float*)d_in[25];
    const float* proj_b   = (const float*)d_in[26];
    const float* cls_w1   = (const float*)d_in[27];
    const float* cls_b1   = (const float*)d_in[28];
    const float* cls_w2   = (const float*)d_in[29];
    const float* cls_b2   = (const float*)d_in[30];
    const int*   src      = (const int*)d_in[31];
    const int*   dst      = (const int*)d_in[32];
    float* out = (float*)d_out;

    size_t o = 0;
    auto carve = [&](size_t nbytes) -> void* {
        void* p = (char*)d_ws + o;
        o += (nbytes + 255) & ~(size_t)255;
        return p;
    };
    float* state = (float*)carve((size_t)NT * H * 4);
    float* xr    = (float*)carve((size_t)NT * FD * 4);
    float* pred  = (float*)carve((size_t)NT * 4);
    float* pre0  = (float*)carve((size_t)NPL * AP * 4);
    float* pre1  = (float*)carve((size_t)NPL * AP * 4);
    int*   counts= (int*)carve((size_t)11 * NPL * 4);
    int*   cursor= (int*)carve((size_t)11 * NPL * 4);
    int*   offs  = (int*)carve((size_t)11 * NPL * 4);
    int*   nbrb  = (int*)carve((size_t)NE * 4);
    float* WaTF  = (float*)carve(H2 * AP * 4);
    float* b2pF  = (float*)carve(64 * 4);
    float* W4iF  = (float*)carve(H2 * 400 * 4);
    float* b4iF  = (float*)carve(400 * 4);
    float* nwTF  = (float*)carve(H2 * NWS * 4);
    float* WaTB  = (float*)carve(H2 * AP * 4);
    float* b2pB  = (float*)carve(64 * 4);
    float* W4iB  = (float*)carve(H2 * 400 * 4);
    float* b4iB  = (float*)carve(400 * 4);
    float* nwTB  = (float*)carve(H2 * NWS * 4);

    // zero counts AND cursor INCLUDING alignment padding between them
    hipMemsetAsync(counts, 0, (size_t)((char*)offs - (char*)counts), stream);

    fold_kernel<<<(2 * 28350 + 255) / 256, 256, 0, stream>>>(
        fpre_w2, fpre_b2, fpost_w1, fpost_w2, fpost_b2, gruf_wh, gruf_bh, gruf_bi, fpre_w1,
        bpre_w2, bpre_b2, bpost_w1, bpost_w2, bpost_b2, grub_wh, grub_bh, grub_bi, bpre_w1,
        WaTF, b2pF, W4iF, b4iF, nwTF,
        WaTB, b2pB, W4iB, b4iB, nwTB);
    csr_count<<<(NE + 255) / 256, 256, 0, stream>>>(src, counts);
    csr_scan<<<11, 256, 0, stream>>>(counts, offs);
    csr_fill<<<(NE + 255) / 256, 256, 0, stream>>>(src, dst, offs, cursor, nbrb);
    pre_init<<<(NPL * AP + 255) / 256, 256, 0, stream>>>(fpre_b1, pre0, pre1);

    float* preBuf[2] = { pre0, pre1 };
    int pb = 0;
    const int k3Grid = NPL / TN;   // 250

    for (int r = 0; r < 2; ++r) {
        const float* xr_use;
        if (r == 0) {
            xr_use = x;
        } else {
            proj_kernel<<<(NT * FD + 255) / 256, 256, 0, stream>>>(state, proj_w, proj_b, xr);
            xr_use = xr;
        }
        // forward levels 1..11
        for (int l = 1; l < NLV; ++l) {
            bool lastf = (l == NLV - 1);
            k3_kernel<<<k3Grid, 512, 0, stream>>>(
                preBuf[pb], preBuf[pb ^ 1],
                src + (size_t)(l - 1) * EPL, (l - 1) * NPL,
                nullptr, nullptr, nullptr,
                xr_use + (size_t)l * NPL * FD,
                WaTF, b2pF, fpost_b1, W4iF, b4iF, gruf_wi, gruf_bi,
                lastf ? nwTB : nwTF, lastf ? bpre_b1 : fpre_b1,
                state + (size_t)l * NPL * H);
            pb ^= 1;
        }
        // backward levels 10..0
        for (int f = NLV - 2; f >= 0; --f) {
            bool lastb = (f == 0);
            k3_kernel<<<k3Grid, 512, 0, stream>>>(
                preBuf[pb], preBuf[pb ^ 1],
                nullptr, 0,
                offs + (size_t)f * NPL, counts + (size_t)f * NPL, nbrb + (size_t)f * EPL,
                xr_use + (size_t)f * NPL * FD,
                WaTB, b2pB, bpost_b1, W4iB, b4iB, grub_wi, grub_bi,
                lastb ? nwTF : nwTB, lastb ? fpre_b1 : bpre_b1,
                state + (size_t)f * NPL * H);
            pb ^= 1;
        }
    }

    cls_kernel<<<(NPL + 255) / 256, 256, 0, stream>>>(state, cls_w1, cls_b1, cls_w2, cls_b2, pred);
    for (int l = 1; l < NLV; ++l)
        gate_kernel<<<(NPL + 255) / 256, 256, 0, stream>>>(
            x, src, pred, l, (l == NLV - 1) ? out : nullptr);
}

// Round 10
// 1718.183 us; speedup vs baseline: 1.5068x; 1.0006x over previous
//
#include <hip/hip_runtime.h>
#include <cstdint>
#include <cstddef>

#define NLV 12
#define NPL 10000
#define KE 3
#define EPL (NPL * KE)   // 30000 edges per level block
#define NE (11 * EPL)    // 330000
#define NT (NLV * NPL)   // 120000 nodes
#define H 100
#define H2 50
#define FD 4
#define DM 30
#define AP 52            // pre50 row stride (13 float4)
#define TN 40            // nodes per block (250 blocks exactly)
#define YS 404           // Y LDS row stride (dwords)
#define HSS 104          // hs LDS row stride
#define NWS 108          // nwT row stride

__device__ __forceinline__ float sigmoidf_(float x) {
    return 1.0f / (1.0f + __expf(-x));
}
__device__ __forceinline__ float tanhf_(float x) {
    float e = __expf(2.0f * x);
    return 1.0f - 2.0f / (e + 1.0f);
}

// ---------------------------------------------------------------------------
// Weight folding per direction (PER = 28350 outputs):
//  WaT[c*52+k] = (w2@pw1)[k][c] ;  b2p[c] = (b2@pw1)[c]
//  W4i[k*400+c]  c=4o+g, k<50:  g0: pw2[k][o]; g1..3: sum_m pw2[k][m]*wh[(g-1)*100+o][m]
//  b4i[c]: g0: pb2[o]; g1: bh[o]+fold+bi[o]; g2: bh[100+o]+fold+bi[100+o]; g3: bh[200+o]+fold
//  nwT[c*108+k] = (k<100) ? w1pre[k*50+c] : 0
// ---------------------------------------------------------------------------
__global__ void fold_kernel(
    const float* __restrict__ w2F, const float* __restrict__ b2F_,
    const float* __restrict__ pw1F, const float* __restrict__ pw2F,
    const float* __restrict__ pb2F, const float* __restrict__ whF,
    const float* __restrict__ bhF, const float* __restrict__ biF,
    const float* __restrict__ w1pF,
    const float* __restrict__ w2B, const float* __restrict__ b2B_,
    const float* __restrict__ pw1B, const float* __restrict__ pw2B,
    const float* __restrict__ pb2B, const float* __restrict__ whB,
    const float* __restrict__ bhB, const float* __restrict__ biB,
    const float* __restrict__ w1pB,
    float* __restrict__ WaTF, float* __restrict__ b2pF,
    float* __restrict__ W4iF, float* __restrict__ b4iF, float* __restrict__ nwTF,
    float* __restrict__ WaTB, float* __restrict__ b2pB,
    float* __restrict__ W4iB, float* __restrict__ b4iB, float* __restrict__ nwTB)
{
    const int PER = 28350;
    int gid = blockIdx.x * blockDim.x + threadIdx.x;
    if (gid >= 2 * PER) return;
    int dir = gid / PER;
    int i = gid - dir * PER;
    const float* w2  = dir ? w2B  : w2F;
    const float* b2  = dir ? b2B_ : b2F_;
    const float* pw1 = dir ? pw1B : pw1F;
    const float* pw2 = dir ? pw2B : pw2F;
    const float* wh  = dir ? whB  : whF;
    const float* bh  = dir ? bhB  : bhF;
    const float* bi  = dir ? biB  : biF;
    const float* pb2 = dir ? pb2B : pb2F;
    const float* w1p = dir ? w1pB : w1pF;
    float* WaT = dir ? WaTB : WaTF;
    float* b2p = dir ? b2pB : b2pF;
    float* W4i = dir ? W4iB : W4iF;
    float* b4i = dir ? b4iB : b4iF;
    float* nwT = dir ? nwTB : nwTF;

    if (i < 2500) {
        int c = i / 50, k = i - c * 50;
        float s = 0.f;
        for (int m = 0; m < 100; ++m) s += w2[k * 100 + m] * pw1[m * 50 + c];
        WaT[c * AP + k] = s;
    } else if (i < 2550) {
        int c = i - 2500;
        float s = 0.f;
        for (int m = 0; m < 100; ++m) s += b2[m] * pw1[m * 50 + c];
        b2p[c] = s;
    } else if (i < 22550) {
        int j = i - 2550;
        int k = j / 400, c = j - k * 400;
        int o = c >> 2, g = c & 3;
        float s;
        if (g == 0) {
            s = pw2[k * 100 + o];
        } else {
            int row = (g - 1) * 100 + o;
            s = 0.f;
            for (int m = 0; m < 100; ++m) s += pw2[k * 100 + m] * wh[row * 100 + m];
        }
        W4i[k * 400 + c] = s;
    } else if (i < 22950) {
        int c = i - 22550;
        int o = c >> 2, g = c & 3;
        float s;
        if (g == 0) {
            s = pb2[o];
        } else {
            int row = (g - 1) * 100 + o;
            s = bh[row];
            for (int m = 0; m < 100; ++m) s += pb2[m] * wh[row * 100 + m];
            if (g == 1) s += bi[o];
            else if (g == 2) s += bi[100 + o];
        }
        b4i[c] = s;
    } else {
        int j = i - 22950;
        int c = j / NWS, k = j - c * NWS;
        nwT[c * NWS + k] = (k < 100) ? w1p[k * 50 + c] : 0.f;
    }
}

// ---------------------------------------------------------------------------
// CSR build (once): group level-f edges by src; store LOCAL dst index.
// counts doubles as per-node in-degree.
// ---------------------------------------------------------------------------
__global__ void csr_count(const int* __restrict__ src, int* __restrict__ counts)
{
    int e = blockIdx.x * blockDim.x + threadIdx.x;
    if (e >= NE) return;
    int f = e / EPL;
    int sl = src[e] - f * NPL;
    atomicAdd(&counts[f * NPL + sl], 1);
}

__global__ void csr_scan(const int* __restrict__ counts, int* __restrict__ offs)
{
    int f = blockIdx.x;
    int t = threadIdx.x;
    const int base = f * NPL;
    const int CH = 40;
    __shared__ int part[256];
    int s = 0;
    for (int k = 0; k < CH; ++k) {
        int idx = t * CH + k;
        if (idx < NPL) s += counts[base + idx];
    }
    part[t] = s;
    __syncthreads();
    if (t == 0) {
        int run = 0;
        for (int j = 0; j < 256; ++j) { int tmp = part[j]; part[j] = run; run += tmp; }
    }
    __syncthreads();
    int run = part[t];
    for (int k = 0; k < CH; ++k) {
        int idx = t * CH + k;
        if (idx < NPL) { offs[base + idx] = run; run += counts[base + idx]; }
    }
}

__global__ void csr_fill(const int* __restrict__ src, const int* __restrict__ dst,
                         const int* __restrict__ offs, int* __restrict__ cursor,
                         int* __restrict__ nbrb)
{
    int e = blockIdx.x * blockDim.x + threadIdx.x;
    if (e >= NE) return;
    int f = e / EPL;
    int sl = src[e] - f * NPL;
    int p = atomicAdd(&cursor[f * NPL + sl], 1);
    nbrb[f * EPL + offs[f * NPL + sl] + p] = dst[e] - (f + 1) * NPL;
}

// pre0 = relu(b1) broadcast (+zero pads); pre1 pads zeroed.
// Pads stay zero forever (phase D writes only cols 0..49), so smA pads = 0.
__global__ void pre_init(const float* __restrict__ b1,
                         float* __restrict__ pre0, float* __restrict__ pre1)
{
    int t = blockIdx.x * blockDim.x + threadIdx.x;
    if (t >= NPL * AP) return;
    int c = t % AP;
    pre0[t] = (c < H2) ? fmaxf(b1[c], 0.f) : 0.f;
    if (c >= H2) pre1[t] = 0.f;
}

// ---------------------------------------------------------------------------
// Fused level step (round-5 structure; phase C register footprint = exactly
// 50 weight VGPRs: Wc[48] constant-indexed + w48,w49 scalars — NO 52-entry
// array. Rounds 7/8/9 showed any indexed local array >50 floats here tips the
// allocator into scratch spills (~4x step regression + 40ms cold dispatch).
// 512 threads, TN=40 nodes/block, 250 blocks.
//  A: gather pre50 rows -> smA
//  B: p50 = relu(agg@WaT + deg*b2p + pb1) -> smP
//  C: Y[n][c] = b4i[c] + smP[n][0..49]·Wc + xs[n]·wx   (gi folded for r,z)
//  GRU: bulk phase per (n,o): r=sig(Y1) z=sig(Y2) t=tanh(inn+r*Y3) -> hs
//  D: pre50_out = relu(nb1 + hs@nwT)
//  E: coalesced state write
// ---------------------------------------------------------------------------
__global__ __launch_bounds__(512) void k3_kernel(
    const float* __restrict__ preIn, float* __restrict__ preOut,
    const int* __restrict__ fedge, int srcbase,
    const int* __restrict__ boffs, const int* __restrict__ bdeg,
    const int* __restrict__ bnbr,
    const float* __restrict__ xrL,
    const float* __restrict__ WaT, const float* __restrict__ b2p,
    const float* __restrict__ pb1,
    const float* __restrict__ W4i, const float* __restrict__ b4i,
    const float* __restrict__ wi, const float* __restrict__ bi,
    const float* __restrict__ nwT, const float* __restrict__ nb1,
    float* __restrict__ state_out)
{
    __shared__ float smA[TN * AP];     //  8.3 KB
    __shared__ float smP[TN * AP];     //  8.3 KB
    __shared__ float sWaT[H2 * AP];    // 10.4 KB
    __shared__ float sNwT[H2 * NWS];   // 21.6 KB
    __shared__ float Y[TN * YS];       // 64.6 KB
    __shared__ float hs[TN * HSS];     // 16.6 KB
    __shared__ float xs[TN * FD];
    __shared__ int sed[TN * KE];
    __shared__ int soff[TN];
    __shared__ int sdeg[TN];

    int tid = threadIdx.x;
    int nb = blockIdx.x * TN;
    int c = tid;                       // output col for phase C
    int g = c & 3, o4 = c >> 2;

    // ---- stage: per-thread weights (global, coalesced rows) ----
    float Wc[48];                      // 12 float4 groups, constant-indexed
    float w48 = 0.f, w49 = 0.f;
    float b4c = 0.f, wx0 = 0.f, wx1 = 0.f, wx2 = 0.f, wx3 = 0.f;
    if (c < 400) {
#pragma unroll
        for (int k = 0; k < 48; ++k) Wc[k] = W4i[k * 400 + c];
        w48 = W4i[48 * 400 + c];
        w49 = W4i[49 * 400 + c];
        b4c = b4i[c];
        if (g == 1 || g == 2) {
            int off = ((g == 1) ? o4 : (100 + o4)) * 4;
            wx0 = wi[off + 0]; wx1 = wi[off + 1]; wx2 = wi[off + 2]; wx3 = wi[off + 3];
        }
    }
    // LDS staging: WaT, nwT, xs, edge metadata
    for (int idx = tid; idx < H2 * AP / 4; idx += 512)
        ((float4*)sWaT)[idx] = ((const float4*)WaT)[idx];
    for (int idx = tid; idx < H2 * NWS / 4; idx += 512)
        ((float4*)sNwT)[idx] = ((const float4*)nwT)[idx];
    if (tid < TN)
        ((float4*)xs)[tid] = ((const float4*)xrL)[nb + tid];
    if (fedge) {
        if (tid < TN * KE) sed[tid] = fedge[nb * KE + tid] - srcbase;
    } else {
        if (tid < TN) { soff[tid] = boffs[nb + tid]; sdeg[tid] = bdeg[nb + tid]; }
    }
    __syncthreads();

    // ---- phase A: gather + sum pre50 rows -> smA ----
    const float4* pre4 = (const float4*)preIn;
    for (int idx = tid; idx < TN * 13; idx += 512) {
        int n = idx / 13, q = idx - n * 13;
        float4 a = make_float4(0.f, 0.f, 0.f, 0.f);
        if (fedge) {
#pragma unroll
            for (int e = 0; e < KE; ++e) {
                int r = sed[KE * n + e];
                float4 v = pre4[r * 13 + q];
                a.x += v.x; a.y += v.y; a.z += v.z; a.w += v.w;
            }
        } else {
            int off = soff[n], d = sdeg[n];
            for (int e = 0; e < d; ++e) {
                int r = bnbr[off + e];
                float4 v = pre4[r * 13 + q];
                a.x += v.x; a.y += v.y; a.z += v.z; a.w += v.w;
            }
        }
        *(float4*)&smA[n * AP + 4 * q] = a;
    }
    __syncthreads();

    // ---- phase B: p50 -> smP (smA pads are exactly 0; WaT pad cols unused
    //      in the product only via smA pads = 0, so result is exact) ----
    for (int idx = tid; idx < TN * H2; idx += 512) {
        int n = idx / H2, cc = idx - n * H2;
        float dgv = fedge ? 3.0f : (float)sdeg[n];
        float acc = pb1[cc] + dgv * b2p[cc];
        const float4* ar = (const float4*)&smA[n * AP];
        const float4* wr = (const float4*)&sWaT[cc * AP];
#pragma unroll
        for (int q = 0; q < 12; ++q) {
            float4 av = ar[q], wv = wr[q];
            acc = fmaf(av.x, wv.x, acc); acc = fmaf(av.y, wv.y, acc);
            acc = fmaf(av.z, wv.z, acc); acc = fmaf(av.w, wv.w, acc);
        }
        // k = 48,49 remainder (skip pads 50,51 entirely)
        float2 a2 = *(const float2*)&smA[n * AP + 48];
        float2 w2v = *(const float2*)&sWaT[cc * AP + 48];
        acc = fmaf(a2.x, w2v.x, acc); acc = fmaf(a2.y, w2v.y, acc);
        smP[n * AP + cc] = fmaxf(acc, 0.f);
    }
    __syncthreads();

    // ---- phase C: Y = b4 + P[0..49]@W4i + xs@wx ----
    if (c < 400) {
#pragma unroll 2
        for (int n = 0; n < TN; ++n) {
            const float4* pr = (const float4*)&smP[n * AP];
            float acc = b4c;
#pragma unroll
            for (int q = 0; q < 12; ++q) {
                float4 pv = pr[q];
                acc = fmaf(pv.x, Wc[4 * q + 0], acc);
                acc = fmaf(pv.y, Wc[4 * q + 1], acc);
                acc = fmaf(pv.z, Wc[4 * q + 2], acc);
                acc = fmaf(pv.w, Wc[4 * q + 3], acc);
            }
            float2 p2 = *(const float2*)&smP[n * AP + 48];
            acc = fmaf(p2.x, w48, acc); acc = fmaf(p2.y, w49, acc);
            float4 xv = *(const float4*)&xs[n * FD];
            acc = fmaf(xv.x, wx0, acc); acc = fmaf(xv.y, wx1, acc);
            acc = fmaf(xv.z, wx2, acc); acc = fmaf(xv.w, wx3, acc);
            Y[n * YS + c] = acc;
        }
    }
    __syncthreads();

    // ---- GRU: per (n,o); o wave-uniform -> wi/bi via s_load ----
    {
        int w8 = __builtin_amdgcn_readfirstlane(tid >> 6);
        int n = tid & 63;
        if (n < TN) {
            float4 xv = *(const float4*)&xs[n * FD];
            for (int o = w8; o < H; o += 8) {
                float4 yv = *(const float4*)&Y[n * YS + 4 * o];
                float inn = bi[200 + o] + xv.x * wi[(200 + o) * 4 + 0]
                                        + xv.y * wi[(200 + o) * 4 + 1]
                                        + xv.z * wi[(200 + o) * 4 + 2]
                                        + xv.w * wi[(200 + o) * 4 + 3];
                float r = sigmoidf_(yv.y);
                float z = sigmoidf_(yv.z);
                float t = tanhf_(inn + r * yv.w);
                hs[n * HSS + o] = fmaf(z, yv.x - t, t);   // (1-z)t + z*m
            }
        }
    }
    __syncthreads();

    // ---- phase D: next step's pre50 ----
    for (int idx = tid; idx < TN * H2; idx += 512) {
        int n = idx / H2, cc = idx - n * H2;
        float acc = nb1[cc];
        const float4* hr = (const float4*)&hs[n * HSS];
        const float4* wr = (const float4*)&sNwT[cc * NWS];
#pragma unroll
        for (int q = 0; q < 25; ++q) {
            float4 hv = hr[q], wv = wr[q];
            acc = fmaf(hv.x, wv.x, acc); acc = fmaf(hv.y, wv.y, acc);
            acc = fmaf(hv.z, wv.z, acc); acc = fmaf(hv.w, wv.w, acc);
        }
        preOut[(size_t)(nb + n) * AP + cc] = fmaxf(acc, 0.f);
    }

    // ---- phase E: coalesced state write ----
    for (int idx = tid; idx < TN * H; idx += 512) {
        int n = idx / H, cc = idx - n * H;
        state_out[(size_t)(nb + n) * H + cc] = hs[n * HSS + cc];
    }
}

// ---------------------------------------------------------------------------
// xr = state @ proj_w + proj_b ; thread = (node, f)
// ---------------------------------------------------------------------------
__global__ __launch_bounds__(256) void proj_kernel(
    const float* __restrict__ state, const float* __restrict__ pw,
    const float* __restrict__ pb, float* __restrict__ xr)
{
    int t = blockIdx.x * 256 + threadIdx.x;
    if (t >= NT * FD) return;
    int node = t >> 2, f = t & 3;
    const float4* rp = (const float4*)(state + (size_t)node * H);
    float acc = pb[f];
    for (int i4 = 0; i4 < 25; ++i4) {
        float4 v = rp[i4];
        acc = fmaf(v.x, pw[(4 * i4 + 0) * 4 + f], acc);
        acc = fmaf(v.y, pw[(4 * i4 + 1) * 4 + f], acc);
        acc = fmaf(v.z, pw[(4 * i4 + 2) * 4 + f], acc);
        acc = fmaf(v.w, pw[(4 * i4 + 3) * 4 + f], acc);
    }
    xr[t] = acc;
}

// ---------------------------------------------------------------------------
// Classification on level-0 nodes only
// ---------------------------------------------------------------------------
__global__ void cls_kernel(const float* __restrict__ state,
                           const float* __restrict__ w1, const float* __restrict__ b1,
                           const float* __restrict__ w2, const float* __restrict__ b2,
                           float* __restrict__ pred)
{
    int n = blockIdx.x * blockDim.x + threadIdx.x;
    if (n >= NPL) return;
    float h[DM];
#pragma unroll
    for (int j = 0; j < DM; ++j) h[j] = b1[j];
    const float* sp = state + (size_t)n * H;
    for (int i = 0; i < H; ++i) {
        float s = sp[i];
#pragma unroll
        for (int j = 0; j < DM; ++j) h[j] = fmaf(s, w1[i * DM + j], h[j]);
    }
    float v = b2[0];
#pragma unroll
    for (int j = 0; j < DM; ++j) v = fmaf(fmaxf(h[j], 0.f), w2[j], v);
    pred[n] = sigmoidf_(v);
}

// ---------------------------------------------------------------------------
// Hard gate evaluation, one level per launch (single-block variant measured
// 253 us in round 8 — keep multi-launch). Final level writes `out` directly.
// ---------------------------------------------------------------------------
__global__ void gate_kernel(const float* __restrict__ x, const int* __restrict__ src,
                            float* __restrict__ pred, int l, float* __restrict__ out)
{
    int j = blockIdx.x * blockDim.x + threadIdx.x;
    if (j >= NPL) return;
    int e0 = (l - 1) * EPL + KE * j;
    int dg = l * NPL + j;
    float v0 = pred[src[e0 + 0]];
    float v1 = pred[src[e0 + 1]];
    float v2 = pred[src[e0 + 2]];
    const float invT = 100.0f;
    float mx = fmaxf(v0, fmaxf(v1, v2));
    float e0x = __expf((v0 - mx) * invT);
    float e1x = __expf((v1 - mx) * invT);
    float e2x = __expf((v2 - mx) * invT);
    float smax = (e0x * v0 + e1x * v1 + e2x * v2) / (e0x + e1x + e2x);
    float mn = fminf(v0, fminf(v1, v2));
    float f0 = __expf((mn - v0) * invT);
    float f1 = __expf((mn - v1) * invT);
    float f2 = __expf((mn - v2) * invT);
    float smin = (f0 * v0 + f1 * v1 + f2 * v2) / (f0 + f1 + f2);
    float am = x[(size_t)dg * FD + 1];
    float om = x[(size_t)dg * FD + 2];
    float nm = x[(size_t)dg * FD + 3];
    float v = am * smin + om * smax + nm * (3.f - (v0 + v1 + v2));
    pred[dg] = v;
    if (out) out[j] = v;
}

// ---------------------------------------------------------------------------
extern "C" void kernel_launch(void* const* d_in, const int* in_sizes, int n_in,
                              void* d_out, int out_size, void* d_ws, size_t ws_size,
                              hipStream_t stream)
{
    const float* x        = (const float*)d_in[0];
    const float* fpre_w1  = (const float*)d_in[1];
    const float* fpre_b1  = (const float*)d_in[2];
    const float* fpre_w2  = (const float*)d_in[3];
    const float* fpre_b2  = (const float*)d_in[4];
    const float* fpost_w1 = (const float*)d_in[5];
    const float* fpost_b1 = (const float*)d_in[6];
    const float* fpost_w2 = (const float*)d_in[7];
    const float* fpost_b2 = (const float*)d_in[8];
    const float* bpre_w1  = (const float*)d_in[9];
    const float* bpre_b1  = (const float*)d_in[10];
    const float* bpre_w2  = (const float*)d_in[11];
    const float* bpre_b2  = (const float*)d_in[12];
    const float* bpost_w1 = (const float*)d_in[13];
    const float* bpost_b1 = (const float*)d_in[14];
    const float* bpost_w2 = (const float*)d_in[15];
    const float* bpost_b2 = (const float*)d_in[16];
    const float* gruf_wi  = (const float*)d_in[17];
    const float* gruf_wh  = (const float*)d_in[18];
    const float* gruf_bi  = (const float*)d_in[19];
    const float* gruf_bh  = (const float*)d_in[20];
    const float* grub_wi  = (const float*)d_in[21];
    const float* grub_wh  = (const float*)d_in[22];
    const float* grub_bi  = (const float*)d_in[23];
    const float* grub_bh  = (const float*)d_in[24];
    const float* proj_w   = (const float*)d_in[25];
    const float* proj_b   = (const float*)d_in[26];
    const float* cls_w1   = (const float*)d_in[27];
    const float* cls_b1   = (const float*)d_in[28];
    const float* cls_w2   = (const float*)d_in[29];
    const float* cls_b2   = (const float*)d_in[30];
    const int*   src      = (const int*)d_in[31];
    const int*   dst      = (const int*)d_in[32];
    float* out = (float*)d_out;

    size_t o = 0;
    auto carve = [&](size_t nbytes) -> void* {
        void* p = (char*)d_ws + o;
        o += (nbytes + 255) & ~(size_t)255;
        return p;
    };
    float* state = (float*)carve((size_t)NT * H * 4);
    float* xr    = (float*)carve((size_t)NT * FD * 4);
    float* pred  = (float*)carve((size_t)NT * 4);
    float* pre0  = (float*)carve((size_t)NPL * AP * 4);
    float* pre1  = (float*)carve((size_t)NPL * AP * 4);
    int*   counts= (int*)carve((size_t)11 * NPL * 4);
    int*   cursor= (int*)carve((size_t)11 * NPL * 4);
    int*   offs  = (int*)carve((size_t)11 * NPL * 4);
    int*   nbrb  = (int*)carve((size_t)NE * 4);
    float* WaTF  = (float*)carve(H2 * AP * 4);
    float* b2pF  = (float*)carve(64 * 4);
    float* W4iF  = (float*)carve(H2 * 400 * 4);
    float* b4iF  = (float*)carve(400 * 4);
    float* nwTF  = (float*)carve(H2 * NWS * 4);
    float* WaTB  = (float*)carve(H2 * AP * 4);
    float* b2pB  = (float*)carve(64 * 4);
    float* W4iB  = (float*)carve(H2 * 400 * 4);
    float* b4iB  = (float*)carve(400 * 4);
    float* nwTB  = (float*)carve(H2 * NWS * 4);

    // zero counts AND cursor INCLUDING alignment padding between them
    hipMemsetAsync(counts, 0, (size_t)((char*)offs - (char*)counts), stream);

    fold_kernel<<<(2 * 28350 + 255) / 256, 256, 0, stream>>>(
        fpre_w2, fpre_b2, fpost_w1, fpost_w2, fpost_b2, gruf_wh, gruf_bh, gruf_bi, fpre_w1,
        bpre_w2, bpre_b2, bpost_w1, bpost_w2, bpost_b2, grub_wh, grub_bh, grub_bi, bpre_w1,
        WaTF, b2pF, W4iF, b4iF, nwTF,
        WaTB, b2pB, W4iB, b4iB, nwTB);
    csr_count<<<(NE + 255) / 256, 256, 0, stream>>>(src, counts);
    csr_scan<<<11, 256, 0, stream>>>(counts, offs);
    csr_fill<<<(NE + 255) / 256, 256, 0, stream>>>(src, dst, offs, cursor, nbrb);
    pre_init<<<(NPL * AP + 255) / 256, 256, 0, stream>>>(fpre_b1, pre0, pre1);

    float* preBuf[2] = { pre0, pre1 };
    int pb = 0;
    const int k3Grid = NPL / TN;   // 250

    for (int r = 0; r < 2; ++r) {
        const float* xr_use;
        if (r == 0) {
            xr_use = x;
        } else {
            proj_kernel<<<(NT * FD + 255) / 256, 256, 0, stream>>>(state, proj_w, proj_b, xr);
            xr_use = xr;
        }
        // forward levels 1..11
        for (int l = 1; l < NLV; ++l) {
            bool lastf = (l == NLV - 1);
            k3_kernel<<<k3Grid, 512, 0, stream>>>(
                preBuf[pb], preBuf[pb ^ 1],
                src + (size_t)(l - 1) * EPL, (l - 1) * NPL,
                nullptr, nullptr, nullptr,
                xr_use + (size_t)l * NPL * FD,
                WaTF, b2pF, fpost_b1, W4iF, b4iF, gruf_wi, gruf_bi,
                lastf ? nwTB : nwTF, lastf ? bpre_b1 : fpre_b1,
                state + (size_t)l * NPL * H);
            pb ^= 1;
        }
        // backward levels 10..0
        for (int f = NLV - 2; f >= 0; --f) {
            bool lastb = (f == 0);
            k3_kernel<<<k3Grid, 512, 0, stream>>>(
                preBuf[pb], preBuf[pb ^ 1],
                nullptr, 0,
                offs + (size_t)f * NPL, counts + (size_t)f * NPL, nbrb + (size_t)f * EPL,
                xr_use + (size_t)f * NPL * FD,
                WaTB, b2pB, bpost_b1, W4iB, b4iB, grub_wi, grub_bi,
                lastb ? nwTF : nwTB, lastb ? fpre_b1 : bpre_b1,
                state + (size_t)f * NPL * H);
            pb ^= 1;
        }
    }

    cls_kernel<<<(NPL + 255) / 256, 256, 0, stream>>>(state, cls_w1, cls_b1, cls_w2, cls_b2, pred);
    for (int l = 1; l < NLV; ++l)
        gate_kernel<<<(NPL + 255) / 256, 256, 0, stream>>>(
            x, src, pred, l, (l == NLV - 1) ? out : nullptr);
}